// Round 1
// baseline (390.287 us; speedup 1.0000x reference)
//
#include <hip/hip_runtime.h>
#include <hip/hip_bf16.h>
#include <stdint.h>

// ---------------------------------------------------------------------------
// Problem constants
// ---------------------------------------------------------------------------
#define NCLS   6
#define NATOMS 5
#define B_     64
#define P_     196
#define D_     768
#define H_     3072
#define SEQ    (NCLS + P_)        // 202
#define NPATCH (B_ * P_)          // 12544
#define NPAIR  (B_ * NCLS)        // 384

typedef unsigned short ushort_t;
typedef __attribute__((ext_vector_type(8))) short  bf16x8;
typedef __attribute__((ext_vector_type(4))) float  f32x4;

// ---------------------------------------------------------------------------
// Helpers
// ---------------------------------------------------------------------------
__device__ __forceinline__ float gelu_exact(float x) {
    return 0.5f * x * (1.0f + erff(x * 0.70710678118654752440f));
}

// fp32 -> bf16 (round to nearest even), raw bits
__device__ __forceinline__ ushort_t f2bf(float f) {
    uint32_t u = __builtin_bit_cast(uint32_t, f);
    u = (u + 0x7fffu + ((u >> 16) & 1u)) >> 16;
    return (ushort_t)u;
}

// async global -> LDS, 16 bytes per lane (wave-uniform base + lane*16 layout)
__device__ __forceinline__ void gload16(const ushort_t* g, ushort_t* l) {
    __builtin_amdgcn_global_load_lds(
        (const __attribute__((address_space(1))) uint32_t*)g,
        (__attribute__((address_space(3))) uint32_t*)l,
        16, 0, 0);
}

// ---------------------------------------------------------------------------
// fp32 -> bf16 conversion kernels
// ---------------------------------------------------------------------------
__global__ void cvt4_kernel(const float* __restrict__ in, ushort_t* __restrict__ out, int n) {
    int i = (blockIdx.x * blockDim.x + threadIdx.x) * 4;
    if (i >= n) return;
    float4 v = *(const float4*)(in + i);
    ushort_t o0 = f2bf(v.x), o1 = f2bf(v.y), o2 = f2bf(v.z), o3 = f2bf(v.w);
    ushort4 o; o.x = o0; o.y = o1; o.z = o2; o.w = o3;
    *(ushort4*)(out + i) = o;
}

// split x (B, SEQ, D) fp32 into patch tokens (NPATCH, D) bf16 and cls tokens (NPAIR, D) bf16
__global__ void split_x_kernel(const float* __restrict__ x,
                               ushort_t* __restrict__ xp,
                               ushort_t* __restrict__ cls) {
    int i = (blockIdx.x * blockDim.x + threadIdx.x) * 4;
    const int total = B_ * SEQ * D_;
    if (i >= total) return;
    int row = i / D_;
    int col = i - row * D_;   // D_ % 4 == 0 so all 4 elems share a row
    int b = row / SEQ, s = row - b * SEQ;
    float4 v = *(const float4*)(x + i);
    ushort4 o;
    o.x = f2bf(v.x); o.y = f2bf(v.y); o.z = f2bf(v.z); o.w = f2bf(v.w);
    if (s < NCLS) {
        *(ushort4*)(cls + (size_t)(b * NCLS + s) * D_ + col) = o;
    } else {
        *(ushort4*)(xp + (size_t)(b * P_ + (s - NCLS)) * D_ + col) = o;
    }
}

// ---------------------------------------------------------------------------
// Gate: logits, weight, src/dst atom per (b, n) pair. One wave per pair.
// ---------------------------------------------------------------------------
__global__ void gate_kernel(const float* __restrict__ x, const float* __restrict__ gd,
                            int* __restrict__ src, int* __restrict__ dst,
                            float* __restrict__ wgt) {
    int r = blockIdx.x;           // pair index 0..383
    int b = r / NCLS, n = r - b * NCLS;
    const float* xr = x + (size_t)(b * SEQ + n) * D_;
    const float* g  = gd + (size_t)n * D_;
    int lane = threadIdx.x;
    float s = 0.f;
    for (int k = lane; k < D_; k += 64) s += xr[k] * g[k];
    #pragma unroll
    for (int off = 32; off > 0; off >>= 1) s += __shfl_down(s, off, 64);
    if (lane == 0) {
        float logit = s;
        bool left = (logit >= 0.f);
        float p = 1.f / (1.f + expf(-logit));
        float w = left ? p : (1.f - p);
        const int LK[NCLS] = {3, 4, 8, 9, 13, 14};
        const int RK[NCLS] = {15, 20, 16, 21, 17, 22};
        int key = left ? LK[n] : RK[n];
        src[r] = key / NATOMS;
        dst[r] = key % NATOMS;
        wgt[r] = w;
    }
}

// ---------------------------------------------------------------------------
// Templated GEMM:  C[m,n] = sum_k A[m,k] * B[n,k]   (B is "B^T" layout, N x K)
// 128x128 tile, BK=32, 4 waves (2x2), 16x16x32 bf16 MFMA, global_load_lds.
// MODE 0: H1 = bf16(gelu(acc + bias[n]))                       (patch layer 1)
// MODE 1: out[(b*SEQ+NCLS+p)*D_+n] = acc + bias[n]             (patch layer 2)
// MODE 2: if src[m]==atom: HID = bf16(gelu(acc + bias[atom*H_+n]))  (cls in)
// MODE 3: if dst[m]==atom: out[(b*SEQ+nn)*D_+n] = (acc + bias[atom*D_+n])*wgt[m]
// ---------------------------------------------------------------------------
template <int MODE>
__global__ __launch_bounds__(256)
void gemm_bt(const ushort_t* __restrict__ A,
             const ushort_t* __restrict__ Bm,
             int N, int K,
             const float* __restrict__ bias,
             float* __restrict__ outF,
             ushort_t* __restrict__ outB,
             const int* __restrict__ selIdx,
             const float* __restrict__ wgt) {
    const int tile_m = blockIdx.x;
    const int tile_n = blockIdx.y;
    const int atom   = blockIdx.z;

    const ushort_t* Ab = A  + (size_t)tile_m * 128 * K;
    const ushort_t* Bb = Bm + ((size_t)atom * N + (size_t)tile_n * 128) * K;

    __shared__ __align__(16) ushort_t As[128 * 32];
    __shared__ __align__(16) ushort_t Bs[128 * 32];

    const int tid  = threadIdx.x;
    const int lane = tid & 63;
    const int wave = tid >> 6;
    const int wr = wave >> 1;     // wave row (0..1), 64 rows each
    const int wc = wave & 1;      // wave col (0..1), 64 cols each

    f32x4 acc[4][4];
    #pragma unroll
    for (int i = 0; i < 4; i++)
        #pragma unroll
        for (int j = 0; j < 4; j++)
            acc[i][j] = (f32x4){0.f, 0.f, 0.f, 0.f};

    const int ldrow = tid >> 2;          // 0..63
    const int ldk   = (tid & 3) * 8;     // element offset within 32-wide K slab
    ushort_t* AsDst = As + tid * 8;      // linear: lane*16B within wave
    ushort_t* BsDst = Bs + tid * 8;

    const int frow = lane & 15;
    const int fk   = (lane >> 4) * 8;

    for (int k0 = 0; k0 < K; k0 += 32) {
        __syncthreads();   // previous iteration's LDS reads done
        gload16(Ab + (size_t)ldrow * K + k0 + ldk,        AsDst);
        gload16(Ab + (size_t)(64 + ldrow) * K + k0 + ldk, AsDst + 64 * 32);
        gload16(Bb + (size_t)ldrow * K + k0 + ldk,        BsDst);
        gload16(Bb + (size_t)(64 + ldrow) * K + k0 + ldk, BsDst + 64 * 32);
        asm volatile("s_waitcnt vmcnt(0)" ::: "memory");
        __syncthreads();

        bf16x8 afrag[4], bfrag[4];
        #pragma unroll
        for (int mi = 0; mi < 4; mi++)
            afrag[mi] = *(const bf16x8*)(As + (wr * 64 + mi * 16 + frow) * 32 + fk);
        #pragma unroll
        for (int ni = 0; ni < 4; ni++)
            bfrag[ni] = *(const bf16x8*)(Bs + (wc * 64 + ni * 16 + frow) * 32 + fk);

        #pragma unroll
        for (int mi = 0; mi < 4; mi++)
            #pragma unroll
            for (int ni = 0; ni < 4; ni++)
                acc[mi][ni] = __builtin_amdgcn_mfma_f32_16x16x32_bf16(
                    afrag[mi], bfrag[ni], acc[mi][ni], 0, 0, 0);
    }

    // epilogue: C/D layout col = lane&15, row = (lane>>4)*4 + reg
    const int fq = lane >> 4;
    #pragma unroll
    for (int mi = 0; mi < 4; mi++) {
        #pragma unroll
        for (int ni = 0; ni < 4; ni++) {
            #pragma unroll
            for (int r = 0; r < 4; r++) {
                int m = tile_m * 128 + wr * 64 + mi * 16 + fq * 4 + r;
                int n = tile_n * 128 + wc * 64 + ni * 16 + frow;
                float v = acc[mi][ni][r];
                if constexpr (MODE == 0) {
                    v = gelu_exact(v + bias[n]);
                    outB[(size_t)m * N + n] = f2bf(v);
                } else if constexpr (MODE == 1) {
                    int b = m / P_, p = m - b * P_;
                    outF[(size_t)(b * SEQ + NCLS + p) * D_ + n] = v + bias[n];
                } else if constexpr (MODE == 2) {
                    if (selIdx[m] == atom) {
                        v = gelu_exact(v + bias[atom * H_ + n]);
                        outB[(size_t)m * N + n] = f2bf(v);
                    }
                } else { // MODE 3
                    if (selIdx[m] == atom) {
                        int b = m / NCLS, nn = m - b * NCLS;
                        outF[(size_t)(b * SEQ + nn) * D_ + n] =
                            (v + bias[atom * D_ + n]) * wgt[m];
                    }
                }
            }
        }
    }
}

// ---------------------------------------------------------------------------
// Launch
// ---------------------------------------------------------------------------
extern "C" void kernel_launch(void* const* d_in, const int* in_sizes, int n_in,
                              void* d_out, int out_size, void* d_ws, size_t ws_size,
                              hipStream_t stream) {
    const float* x   = (const float*)d_in[0];
    const float* w1  = (const float*)d_in[1];
    const float* b1  = (const float*)d_in[2];
    const float* w2  = (const float*)d_in[3];
    const float* b2  = (const float*)d_in[4];
    const float* gd  = (const float*)d_in[5];
    const float* aiw = (const float*)d_in[6];
    const float* aib = (const float*)d_in[7];
    const float* aow = (const float*)d_in[8];
    const float* aob = (const float*)d_in[9];
    float* out = (float*)d_out;

    // workspace layout (all 16B aligned; total ~149 MiB)
    char* ws = (char*)d_ws;
    ushort_t* Xp   = (ushort_t*)ws; ws += (size_t)NPATCH * D_ * 2;
    ushort_t* W1b  = (ushort_t*)ws; ws += (size_t)H_ * D_ * 2;
    ushort_t* W2b  = (ushort_t*)ws; ws += (size_t)D_ * H_ * 2;
    ushort_t* H1   = (ushort_t*)ws; ws += (size_t)NPATCH * H_ * 2;
    ushort_t* CLSb = (ushort_t*)ws; ws += (size_t)NPAIR * D_ * 2;
    ushort_t* AIWb = (ushort_t*)ws; ws += (size_t)NATOMS * H_ * D_ * 2;
    ushort_t* AOWb = (ushort_t*)ws; ws += (size_t)NATOMS * D_ * H_ * 2;
    ushort_t* HID  = (ushort_t*)ws; ws += (size_t)NPAIR * H_ * 2;
    int*   SRC = (int*)ws;   ws += NPAIR * 4;
    int*   DST = (int*)ws;   ws += NPAIR * 4;
    float* WGT = (float*)ws; ws += NPAIR * 4;

    // conversions
    split_x_kernel<<<(B_ * SEQ * D_ / 4 + 255) / 256, 256, 0, stream>>>(x, Xp, CLSb);
    cvt4_kernel<<<(H_ * D_ / 4 + 255) / 256, 256, 0, stream>>>(w1, W1b, H_ * D_);
    cvt4_kernel<<<(D_ * H_ / 4 + 255) / 256, 256, 0, stream>>>(w2, W2b, D_ * H_);
    cvt4_kernel<<<(NATOMS * H_ * D_ / 4 + 255) / 256, 256, 0, stream>>>(aiw, AIWb, NATOMS * H_ * D_);
    cvt4_kernel<<<(NATOMS * D_ * H_ / 4 + 255) / 256, 256, 0, stream>>>(aow, AOWb, NATOMS * D_ * H_);
    gate_kernel<<<NPAIR, 64, 0, stream>>>(x, gd, SRC, DST, WGT);

    // patch MLP: (12544x768)@(3072x768)^T -> gelu -> (12544x3072)@(768x3072)^T
    gemm_bt<0><<<dim3(NPATCH / 128, H_ / 128, 1), 256, 0, stream>>>(
        Xp, W1b, H_, D_, b1, nullptr, H1, nullptr, nullptr);
    gemm_bt<1><<<dim3(NPATCH / 128, D_ / 128, 1), 256, 0, stream>>>(
        H1, W2b, D_, H_, b2, out, nullptr, nullptr, nullptr);

    // cls path: dense all-atom GEMMs with masked epilogue scatter
    gemm_bt<2><<<dim3(NPAIR / 128, H_ / 128, NATOMS), 256, 0, stream>>>(
        CLSb, AIWb, H_, D_, aib, nullptr, HID, SRC, nullptr);
    gemm_bt<3><<<dim3(NPAIR / 128, D_ / 128, NATOMS), 256, 0, stream>>>(
        HID, AOWb, D_, H_, aob, out, nullptr, DST, WGT);
}